// Round 1
// 349.210 us; speedup vs baseline: 1.0689x; 1.0689x over previous
//
#include <hip/hip_runtime.h>

// Problem constants
#define Bn 8
#define Tn 2048
#define Dn 1024
#define Hn 1024
#define Mn (Bn * Tn)  // 16384 flattened rows of x

typedef __attribute__((ext_vector_type(8))) short bf16x8;    // 8 bf16 = 4 VGPRs (MFMA A/B frag)
typedef __attribute__((ext_vector_type(4))) short short4v;   // 4 bf16 = 8B store
typedef __attribute__((ext_vector_type(16))) float f32x16;   // 32x32 MFMA C/D frag
typedef __attribute__((ext_vector_type(4))) float f32x4;     // 16x16 MFMA C/D frag

__device__ __forceinline__ unsigned short f2bf(float f) {
  union { float f; unsigned int u; } v; v.f = f;
  unsigned int u = v.u;
  u += 0x7FFFu + ((u >> 16) & 1u);   // RNE
  return (unsigned short)(u >> 16);
}
__device__ __forceinline__ float bf2f(unsigned short h) {
  union { unsigned int u; float f; } v; v.u = ((unsigned int)h) << 16;
  return v.f;
}

// async global->LDS, 16B per lane; lds base must be wave-uniform (lane writes base + lane*16B)
__device__ __forceinline__ void gload_lds16(const unsigned short* g, unsigned short* l) {
  __builtin_amdgcn_global_load_lds((const __attribute__((address_space(1))) void*)g,
                                   (__attribute__((address_space(3))) void*)l, 16, 0, 0);
}

// Chunk swizzle s(r) = (r&3) ^ ((r>>2)&3): LDS slot (row, q) holds global 16B chunk q ^ s(row).
// Period 16 in rows -> a 16-row ds_read_b128 column read hits all 8 bank slots exactly 2x
// (2-way = free, m136); a 32-row read is an even 4-way. Old swizzle (q ^ (r&3)) was 8-way.

// Swizzled staging of a 128x32-short tile (4 waves x 32 rows).
__device__ __forceinline__ void stage128x32s(const unsigned short* gbase, size_t row_stride,
                                             unsigned short* lds, int wave, int lane) {
#pragma unroll
  for (int c = 0; c < 2; ++c) {
    int rl = c * 16 + (lane >> 2);          // row within this wave's 32-row strip
    int pos = (lane & 3) ^ (rl & 3) ^ ((rl >> 2) & 3);
    const unsigned short* g = gbase + (size_t)(wave * 32 + rl) * row_stride + pos * 8;
    gload_lds16(g, lds + (wave * 32 + c * 16) * 32);
  }
}
__device__ __forceinline__ void stage128x64s(const unsigned short* gbase, size_t row_stride,
                                             unsigned short* lds0, unsigned short* lds1,
                                             int wave, int lane) {
  stage128x32s(gbase, row_stride, lds0, wave, lane);
  stage128x32s(gbase + 32, row_stride, lds1, wave, lane);
}

// Swizzled staging of a 256x32-short tile (8 waves x 32 rows). Same swizzle.
__device__ __forceinline__ void stage256x32s(const unsigned short* gbase, size_t row_stride,
                                             unsigned short* lds, int wave, int lane) {
#pragma unroll
  for (int c = 0; c < 2; ++c) {
    int rl = c * 16 + (lane >> 2);
    int pos = (lane & 3) ^ (rl & 3) ^ ((rl >> 2) & 3);
    const unsigned short* g = gbase + (size_t)(wave * 32 + rl) * row_stride + pos * 8;
    gload_lds16(g, lds + (wave * 32 + c * 16) * 32);
  }
}

// One BK=32 buffer of 32x32x16 MFMAs: 2 k-steps, 2x2 subtiles of the 64x64 wave tile.
// (used by gemm_scores / gemm_out; 2-phase structure)
__device__ __forceinline__ void mma_bk32(const unsigned short* lA, const unsigned short* lB,
                                         int wr, int wc, int l32, int half,
                                         f32x16 acc[2][2]) {
#pragma unroll
  for (int kk = 0; kk < 2; ++kk) {
    const int pos = (kk * 2 + half) ^ (l32 & 3) ^ ((l32 >> 2) & 3);
    bf16x8 af[2], bfr[2];
#pragma unroll
    for (int m = 0; m < 2; ++m)
      af[m] = *(const bf16x8*)&lA[(wr + m * 32 + l32) * 32 + pos * 8];
#pragma unroll
    for (int n = 0; n < 2; ++n)
      bfr[n] = *(const bf16x8*)&lB[(wc + n * 32 + l32) * 32 + pos * 8];
#pragma unroll
    for (int m = 0; m < 2; ++m)
#pragma unroll
      for (int n = 0; n < 2; ++n)
        acc[m][n] = __builtin_amdgcn_mfma_f32_32x32x16_bf16(af[m], bfr[n], acc[m][n], 0, 0, 0);
  }
}

// ---------------- fp32 -> bf16 convert (x) ----------------
__global__ __launch_bounds__(256) void k_convert(const float* __restrict__ in,
                                                 unsigned short* __restrict__ out, int n4) {
  int idx = blockIdx.x * 256 + threadIdx.x;
  if (idx >= n4) return;
  float4 v = ((const float4*)in)[idx];
  short4v o;
  o.x = (short)f2bf(v.x); o.y = (short)f2bf(v.y);
  o.z = (short)f2bf(v.z); o.w = (short)f2bf(v.w);
  *(short4v*)(out + (size_t)idx * 4) = o;
}

// ---------------- W fp32 [k][n] -> bf16 Wt [n][k], 3 weights in one dispatch ----------------
__global__ __launch_bounds__(256) void k_cvt_w_t(const float* __restrict__ W0,
                                                 const float* __restrict__ W1,
                                                 const float* __restrict__ W2,
                                                 unsigned short* __restrict__ Wt3) {
  const int n0 = blockIdx.x * 64, k0 = blockIdx.y * 64, w = blockIdx.z;
  const float* W = (w == 0) ? W0 : (w == 1) ? W1 : W2;
  unsigned short* Wt = Wt3 + (size_t)w * Hn * Dn;
  __shared__ unsigned short lT[64 * 65];
  const int tid = threadIdx.x;
#pragma unroll
  for (int p = 0; p < 2; ++p) {
    int o = tid + p * 256;
    int r = o >> 3, c = (o & 7) * 8;  // r = k offset, c = n offset
    const float* src = W + (size_t)(k0 + r) * Hn + n0 + c;
    float4 v0 = *(const float4*)src;
    float4 v1 = *(const float4*)(src + 4);
    unsigned short* d = &lT[r * 65 + c];
    d[0] = f2bf(v0.x); d[1] = f2bf(v0.y); d[2] = f2bf(v0.z); d[3] = f2bf(v0.w);
    d[4] = f2bf(v1.x); d[5] = f2bf(v1.y); d[6] = f2bf(v1.z); d[7] = f2bf(v1.w);
  }
  __syncthreads();
#pragma unroll
  for (int p = 0; p < 2; ++p) {
    int o = tid + p * 256;
    int r2 = o >> 3, c2 = (o & 7) * 8;  // r2 = n offset, c2 = k offset
    bf16x8 v;
#pragma unroll
    for (int s = 0; s < 8; ++s) v[s] = (short)lT[(c2 + s) * 65 + r2];
    *(bf16x8*)(Wt + (size_t)(n0 + r2) * Dn + k0 + c2) = v;
  }
}

// ---------------- Merged QKV projection GEMM: 256x256 tile, 8 waves, counted-vmcnt pipeline ----
// T2+T3+T4+T5 structure: 16x16x32 MFMAs at 8x4 fragment reuse (375 B LDS-read/MFMA),
// double-buffered 128 KiB LDS, stage(t+1) in flight under compute(t) via s_waitcnt vmcnt(8)
// (never 0 in main loop), raw s_barrier (no compiler vmcnt(0) drain), setprio around MFMA.
// Liveness: stage at iter t targets the buffer read at iter t-1; barrier-1 separates.
// grid = 768: XCD c = f&7; 12 n-tiles (3 weights x 4) fastest within XCD; V transposed store.
__global__ __launch_bounds__(512, 2) void gemm_qkv(const unsigned short* __restrict__ A,
                                                   const unsigned short* __restrict__ Wt3,
                                                   unsigned short* __restrict__ Q,
                                                   unsigned short* __restrict__ Kb,
                                                   unsigned short* __restrict__ Vt) {
  const int f = blockIdx.x;
  const int c = f & 7;
  const int q = f >> 3;
  const int nn = q % 12;
  const int w = nn >> 2;                     // 0=Q 1=K 2=V
  const int n0 = (nn & 3) * 256;
  const int m0 = ((q / 12) * 8 + c) * 256;   // m-tile pinned to XCD c
  const unsigned short* Bw = Wt3 + (size_t)w * Hn * Dn;
  __shared__ unsigned short lds[2][4][256 * 32];  // [dbuf][A-h0,A-h1,B-h0,B-h1][256x32] = 128 KiB
  const int tid = threadIdx.x;
  const int lane = tid & 63, wave = tid >> 6;
  const int wr = (wave >> 2) * 128;          // wave 128-row strip (2 M-groups)
  const int wc = (wave & 3) * 64;            // wave 64-col strip (4 N-groups)
  const int rl15 = lane & 15, l4 = lane >> 4;
  // read chunk for 16x16x32 frags: global k-group (l4) ^ s(row); row bits 0-3 == lane bits 0-3
  const int csw = (l4 ^ (lane & 3) ^ ((lane >> 2) & 3)) & 3;

  f32x4 acc[8][4];
#pragma unroll
  for (int m = 0; m < 8; ++m)
#pragma unroll
    for (int n = 0; n < 4; ++n) acc[m][n] = (f32x4)(0.f);

  const unsigned short* Ab = A + (size_t)m0 * Dn;
  const unsigned short* Bb = Bw + (size_t)n0 * Dn;

  // stage K-tile kt (64 cols) into dbuf d: 4 pieces x 2 loads = 8 global_load_lds per lane
  auto stage_tile = [&](int kt, int d) {
#pragma unroll
    for (int h = 0; h < 2; ++h) {
      stage256x32s(Ab + kt * 64 + h * 32, Dn, &lds[d][h][0], wave, lane);
      stage256x32s(Bb + kt * 64 + h * 32, Dn, &lds[d][2 + h][0], wave, lane);
    }
  };

  // 4 quadrant sub-phases per K-tile: 24 ds_read_b128 + 64 MFMA per wave (min LDS traffic)
  auto compute_tile = [&](int d) {
    const unsigned short* pa = &lds[d][0][0];
    const unsigned short* pb = &lds[d][2][0];
    bf16x8 af[4][2], bf[4][2];
    // q0: load af(m0-3), bf(n0-1); MFMA (m0-3)x(n0-1)
#pragma unroll
    for (int m = 0; m < 4; ++m)
#pragma unroll
      for (int h = 0; h < 2; ++h)
        af[m][h] = *(const bf16x8*)&pa[h * 8192 + (wr + m * 16 + rl15) * 32 + csw * 8];
#pragma unroll
    for (int n = 0; n < 2; ++n)
#pragma unroll
      for (int h = 0; h < 2; ++h)
        bf[n][h] = *(const bf16x8*)&pb[h * 8192 + (wc + n * 16 + rl15) * 32 + csw * 8];
    __builtin_amdgcn_s_setprio(1);
#pragma unroll
    for (int m = 0; m < 4; ++m)
#pragma unroll
      for (int n = 0; n < 2; ++n)
#pragma unroll
        for (int h = 0; h < 2; ++h)
          acc[m][n] = __builtin_amdgcn_mfma_f32_16x16x32_bf16(af[m][h], bf[n][h], acc[m][n], 0, 0, 0);
    __builtin_amdgcn_s_setprio(0);
    // q1: load bf(n2-3); MFMA (m0-3)x(n2-3)
#pragma unroll
    for (int n = 2; n < 4; ++n)
#pragma unroll
      for (int h = 0; h < 2; ++h)
        bf[n][h] = *(const bf16x8*)&pb[h * 8192 + (wc + n * 16 + rl15) * 32 + csw * 8];
    __builtin_amdgcn_s_setprio(1);
#pragma unroll
    for (int m = 0; m < 4; ++m)
#pragma unroll
      for (int n = 2; n < 4; ++n)
#pragma unroll
        for (int h = 0; h < 2; ++h)
          acc[m][n] = __builtin_amdgcn_mfma_f32_16x16x32_bf16(af[m][h], bf[n][h], acc[m][n], 0, 0, 0);
    __builtin_amdgcn_s_setprio(0);
    // q2: reload af <- (m4-7); MFMA (m4-7)x(n2-3)
#pragma unroll
    for (int m = 0; m < 4; ++m)
#pragma unroll
      for (int h = 0; h < 2; ++h)
        af[m][h] = *(const bf16x8*)&pa[h * 8192 + (wr + (m + 4) * 16 + rl15) * 32 + csw * 8];
    __builtin_amdgcn_s_setprio(1);
#pragma unroll
    for (int m = 0; m < 4; ++m)
#pragma unroll
      for (int n = 2; n < 4; ++n)
#pragma unroll
        for (int h = 0; h < 2; ++h)
          acc[m + 4][n] = __builtin_amdgcn_mfma_f32_16x16x32_bf16(af[m][h], bf[n][h], acc[m + 4][n], 0, 0, 0);
    __builtin_amdgcn_s_setprio(0);
    // q3: MFMA (m4-7)x(n0-1), bf(n0-1) still live
    __builtin_amdgcn_s_setprio(1);
#pragma unroll
    for (int m = 0; m < 4; ++m)
#pragma unroll
      for (int n = 0; n < 2; ++n)
#pragma unroll
        for (int h = 0; h < 2; ++h)
          acc[m + 4][n] = __builtin_amdgcn_mfma_f32_16x16x32_bf16(af[m][h], bf[n][h], acc[m + 4][n], 0, 0, 0);
    __builtin_amdgcn_s_setprio(0);
  };

  stage_tile(0, 0);
  for (int kt = 0; kt < Dn / 64 - 1; ++kt) {
    const int d = kt & 1;
    __builtin_amdgcn_s_barrier();            // all waves done reading lds[d^1] (iter kt-1)
    stage_tile(kt + 1, d ^ 1);               // 8 loads, land under compute(kt)
    asm volatile("s_waitcnt vmcnt(8)" ::: "memory");  // tile kt's 8 loads done (not kt+1's)
    __builtin_amdgcn_s_barrier();            // collectively: tile kt staged
    compute_tile(d);
  }
  asm volatile("s_waitcnt vmcnt(0)" ::: "memory");    // drain last tile's loads
  __builtin_amdgcn_s_barrier();
  compute_tile(1);                           // kt = 15, d = 1

  // epilogue: C/D layout col=lane&15, row=l4*4+reg
  if (w != 2) {
    unsigned short* Cp = (w == 0) ? Q : Kb;
#pragma unroll
    for (int m = 0; m < 8; ++m) {
      const int row = m0 + wr + m * 16 + l4 * 4;
#pragma unroll
      for (int n = 0; n < 4; ++n) {
        const int col = n0 + wc + n * 16 + rl15;
#pragma unroll
        for (int r = 0; r < 4; ++r)
          Cp[(size_t)(row + r) * Hn + col] = f2bf(acc[m][n][r]);
      }
    }
  } else {
    // V: write transposed per-batch [h][t]; regs 0..3 = 4 consecutive t -> 8B store
    const int bb = m0 >> 11;  // tile never crosses batch (2048 % 256 == 0)
    const int tb = m0 & 2047;
#pragma unroll
    for (int m = 0; m < 8; ++m) {
      const int t0 = tb + wr + m * 16 + l4 * 4;
#pragma unroll
      for (int n = 0; n < 4; ++n) {
        const int h = n0 + wc + n * 16 + rl15;
        short4v o;
        o.x = (short)f2bf(acc[m][n][0]);
        o.y = (short)f2bf(acc[m][n][1]);
        o.z = (short)f2bf(acc[m][n][2]);
        o.w = (short)f2bf(acc[m][n][3]);
        *(short4v*)(Vt + ((size_t)bb * Hn + h) * Tn + t0) = o;
      }
    }
  }
}

// Scores: E[i][j] = exp((Q[i]·K[j])/32), causal-masked to 0, bf16. BK=64, causal tile skip.
__global__ __launch_bounds__(256) void gemm_scores(const unsigned short* __restrict__ Q,
                                                   const unsigned short* __restrict__ K,
                                                   unsigned short* __restrict__ S) {
  const int f = blockIdx.x;
  const int b = f & 7;
  const int q = f >> 3;
  const int rt = 15 - (q & 15);
  const int ct = q >> 4;
  if (ct > rt) return;
  const int j0 = ct * 128, i0 = rt * 128;
  const unsigned short* Qb = Q + (size_t)b * Tn * Hn;
  const unsigned short* Kp = K + (size_t)b * Tn * Hn;
  unsigned short* Sb = S + (size_t)b * Tn * Tn;
  __shared__ unsigned short lA[2][128 * 32];
  __shared__ unsigned short lB[2][128 * 32];
  const int tid = threadIdx.x;
  const int lane = tid & 63, wave = tid >> 6;
  const int wr = (wave >> 1) * 64, wc = (wave & 1) * 64;
  const int l32 = lane & 31, half = lane >> 5;

  f32x16 acc[2][2];
#pragma unroll
  for (int m = 0; m < 2; ++m)
#pragma unroll
    for (int n = 0; n < 2; ++n) acc[m][n] = (f32x16)(0.f);

  for (int kt = 0; kt < Hn / 64; ++kt) {
    stage128x64s(Qb + (size_t)i0 * Hn + kt * 64, Hn, lA[0], lA[1], wave, lane);
    stage128x64s(Kp + (size_t)j0 * Hn + kt * 64, Hn, lB[0], lB[1], wave, lane);
    __syncthreads();
    mma_bk32(lA[0], lB[0], wr, wc, l32, half, acc);
    mma_bk32(lA[1], lB[1], wr, wc, l32, half, acc);
    __syncthreads();
  }
  // E = exp(s/32), masked above diagonal. No row-max needed: s ~ N(0,1), f32-safe.
#pragma unroll
  for (int m = 0; m < 2; ++m)
#pragma unroll
    for (int n = 0; n < 2; ++n) {
      int col = j0 + wc + n * 32 + l32;
#pragma unroll
      for (int qd = 0; qd < 4; ++qd) {
        int rb = i0 + wr + m * 32 + 8 * qd + 4 * half;
#pragma unroll
        for (int rr = 0; rr < 4; ++rr) {
          int row = rb + rr;
          float e = (col <= row) ? __expf(acc[m][n][qd * 4 + rr] * 0.03125f) : 0.f;
          Sb[(size_t)row * Tn + col] = f2bf(e);
        }
      }
    }
}

// ---------------- row sums of E (softmax denominators) ----------------
__global__ __launch_bounds__(256) void k_rowsum(const unsigned short* __restrict__ S,
                                                float* __restrict__ l) {
  const int b = blockIdx.y;
  const int i = blockIdx.x * 4 + (threadIdx.x >> 6);
  const int lane = threadIdx.x & 63;
  const unsigned short* row = S + ((size_t)b * Tn + i) * (size_t)Tn;
  const int npad = ((i >> 7) + 1) << 7;
  float s = 0.f;
  for (int j0 = 0; j0 < npad; j0 += 512) {
    int j = j0 + lane * 8;
    if (j < npad) {
      bf16x8 v = *(const bf16x8*)(row + j);
#pragma unroll
      for (int t = 0; t < 8; ++t) s += bf2f((unsigned short)v[t]);
    }
  }
#pragma unroll
  for (int off = 32; off > 0; off >>= 1) s += __shfl_down(s, off);
  if (lane == 0) l[(size_t)b * Tn + i] = s;
}

// Output: O[i][h] = (1/l_i) * sum_k E[i][k] * Vt[h][k], causal k limit, BK=64, 32x32 MFMA.
__global__ __launch_bounds__(256) void gemm_out(const unsigned short* __restrict__ P,
                                                const unsigned short* __restrict__ Vt,
                                                const float* __restrict__ lbuf,
                                                float* __restrict__ O) {
  const int f = blockIdx.x;
  const int b = f & 7;
  const int q = f >> 3;
  const int n0 = (q & 7) * 128;
  const int rt = 15 - (q >> 3);
  const int i0 = rt * 128;
  const int nkt = (rt + 1) * 2;  // BK=64 iters: k < (rt+1)*128
  const unsigned short* Pb = P + (size_t)b * Tn * Tn;
  const unsigned short* Vb = Vt + (size_t)b * Tn * Hn;
  __shared__ unsigned short lA[2][128 * 32];
  __shared__ unsigned short lB[2][128 * 32];
  const int tid = threadIdx.x;
  const int lane = tid & 63, wave = tid >> 6;
  const int wr = (wave >> 1) * 64, wc = (wave & 1) * 64;
  const int l32 = lane & 31, half = lane >> 5;

  f32x16 acc[2][2];
#pragma unroll
  for (int m = 0; m < 2; ++m)
#pragma unroll
    for (int n = 0; n < 2; ++n) acc[m][n] = (f32x16)(0.f);

  for (int kt = 0; kt < nkt; ++kt) {
    stage128x64s(Pb + (size_t)i0 * Tn + kt * 64, Tn, lA[0], lA[1], wave, lane);
    stage128x64s(Vb + (size_t)n0 * Tn + kt * 64, Tn, lB[0], lB[1], wave, lane);
    __syncthreads();
    mma_bk32(lA[0], lB[0], wr, wc, l32, half, acc);
    mma_bk32(lA[1], lB[1], wr, wc, l32, half, acc);
    __syncthreads();
  }
#pragma unroll
  for (int m = 0; m < 2; ++m)
#pragma unroll
    for (int n = 0; n < 2; ++n) {
      int col = n0 + wc + n * 32 + l32;
#pragma unroll
      for (int qd = 0; qd < 4; ++qd) {
        int rb = i0 + wr + m * 32 + 8 * qd + 4 * half;
        float4 lv = *(const float4*)&lbuf[(size_t)b * Tn + rb];  // rb % 4 == 0
#pragma unroll
        for (int rr = 0; rr < 4; ++rr) {
          float inv = 1.f / ((&lv.x)[rr]);
          O[((size_t)b * Tn + rb + rr) * Hn + col] = acc[m][n][qd * 4 + rr] * inv;
        }
      }
    }
}

extern "C" void kernel_launch(void* const* d_in, const int* in_sizes, int n_in,
                              void* d_out, int out_size, void* d_ws, size_t ws_size,
                              hipStream_t stream) {
  const float* x  = (const float*)d_in[0];
  const float* Wq = (const float*)d_in[1];
  const float* Wk = (const float*)d_in[2];
  const float* Wv = (const float*)d_in[3];
  float* out = (float*)d_out;

  // workspace layout (bytes); total 198 MiB
  char* ws = (char*)d_ws;
  const size_t MiB = 1024 * 1024;
  unsigned short* Wt3 = (unsigned short*)(ws + 0 * MiB);    // 3 x 2 MiB, stacked q,k,v
  unsigned short* xb  = (unsigned short*)(ws + 6 * MiB);    // 32 MiB; dead after projections
  unsigned short* Qb  = (unsigned short*)(ws + 38 * MiB);
  unsigned short* Kb  = (unsigned short*)(ws + 70 * MiB);
  unsigned short* Vt  = (unsigned short*)(ws + 102 * MiB);  // V, transposed per-batch [h][t]
  unsigned short* S   = (unsigned short*)(ws + 134 * MiB);  // 64 MiB, holds E = exp(scores)
  float*          lrow = (float*)(ws + 6 * MiB);            // 64 KiB in xb's dead region

  // 1. convert x to bf16
  {
    int n4 = (Mn * Dn) / 4;
    k_convert<<<dim3(n4 / 256), 256, 0, stream>>>(x, xb, n4);
  }
  // 2. convert+transpose all 3 weights (one dispatch)
  {
    dim3 g(Hn / 64, Dn / 64, 3);
    k_cvt_w_t<<<g, 256, 0, stream>>>(Wq, Wk, Wv, Wt3);
  }
  // 3. merged Q/K/V projections (V stored transposed), 256^2 pipelined tiles
  {
    gemm_qkv<<<dim3(768), 512, 0, stream>>>(xb, Wt3, Qb, Kb, Vt);
  }
  // 4. scores -> E = exp(s), causal-masked
  {
    gemm_scores<<<dim3(2048), 256, 0, stream>>>(Qb, Kb, S);
  }
  // 5. row sums (softmax denominators)
  {
    k_rowsum<<<dim3(Tn / 4, Bn), 256, 0, stream>>>(S, lrow);
  }
  // 6. output with 1/l scaling
  {
    gemm_out<<<dim3(1024), 256, 0, stream>>>(S, Vt, lrow, out);
  }
}

// Round 3
// 334.186 us; speedup vs baseline: 1.1169x; 1.0450x over previous
//
#include <hip/hip_runtime.h>

// Problem constants
#define Bn 8
#define Tn 2048
#define Dn 1024
#define Hn 1024
#define Mn (Bn * Tn)  // 16384 flattened rows of x

typedef __attribute__((ext_vector_type(8))) short bf16x8;    // 8 bf16 = 4 VGPRs (MFMA A/B frag)
typedef __attribute__((ext_vector_type(4))) short short4v;   // 4 bf16 = 8B store
typedef __attribute__((ext_vector_type(16))) float f32x16;   // 32x32 MFMA C/D frag
typedef __attribute__((ext_vector_type(4))) float f32x4;     // 16x16 MFMA C/D frag

__device__ __forceinline__ unsigned short f2bf(float f) {
  union { float f; unsigned int u; } v; v.f = f;
  unsigned int u = v.u;
  u += 0x7FFFu + ((u >> 16) & 1u);   // RNE
  return (unsigned short)(u >> 16);
}
__device__ __forceinline__ float bf2f(unsigned short h) {
  union { unsigned int u; float f; } v; v.u = ((unsigned int)h) << 16;
  return v.f;
}

// async global->LDS, 16B per lane; lds base must be wave-uniform (lane writes base + lane*16B)
__device__ __forceinline__ void gload_lds16(const unsigned short* g, unsigned short* l) {
  __builtin_amdgcn_global_load_lds((const __attribute__((address_space(1))) void*)g,
                                   (__attribute__((address_space(3))) void*)l, 16, 0, 0);
}

// Chunk swizzle s(r) = (r&3) ^ ((r>>2)&3): LDS slot (row, q) holds global 16B chunk q ^ s(row).
// Period 16 in rows -> fragment reads (16 rows per 16-lane group at fixed k-chunk) spread
// evenly over all 8 16B bank slots.

// Swizzled staging of a 128x32-short tile (4 waves x 32 rows).
__device__ __forceinline__ void stage128x32s(const unsigned short* gbase, size_t row_stride,
                                             unsigned short* lds, int wave, int lane) {
#pragma unroll
  for (int c = 0; c < 2; ++c) {
    int rl = c * 16 + (lane >> 2);          // row within this wave's 32-row strip
    int pos = (lane & 3) ^ (rl & 3) ^ ((rl >> 2) & 3);
    const unsigned short* g = gbase + (size_t)(wave * 32 + rl) * row_stride + pos * 8;
    gload_lds16(g, lds + (wave * 32 + c * 16) * 32);
  }
}
__device__ __forceinline__ void stage128x64s(const unsigned short* gbase, size_t row_stride,
                                             unsigned short* lds0, unsigned short* lds1,
                                             int wave, int lane) {
  stage128x32s(gbase, row_stride, lds0, wave, lane);
  stage128x32s(gbase + 32, row_stride, lds1, wave, lane);
}

// Swizzled staging of a 256x32-short tile (8 waves x 32 rows). Same swizzle. 2 vmem/lane.
__device__ __forceinline__ void stage256x32s(const unsigned short* gbase, size_t row_stride,
                                             unsigned short* lds, int wave, int lane) {
#pragma unroll
  for (int c = 0; c < 2; ++c) {
    int rl = c * 16 + (lane >> 2);
    int pos = (lane & 3) ^ (rl & 3) ^ ((rl >> 2) & 3);
    const unsigned short* g = gbase + (size_t)(wave * 32 + rl) * row_stride + pos * 8;
    gload_lds16(g, lds + (wave * 32 + c * 16) * 32);
  }
}

// One BK=32 buffer of 32x32x16 MFMAs: 2 k-steps, 2x2 subtiles of the 64x64 wave tile.
// (used by gemm_scores / gemm_out; 2-phase structure)
__device__ __forceinline__ void mma_bk32(const unsigned short* lA, const unsigned short* lB,
                                         int wr, int wc, int l32, int half,
                                         f32x16 acc[2][2]) {
#pragma unroll
  for (int kk = 0; kk < 2; ++kk) {
    const int pos = (kk * 2 + half) ^ (l32 & 3) ^ ((l32 >> 2) & 3);
    bf16x8 af[2], bfr[2];
#pragma unroll
    for (int m = 0; m < 2; ++m)
      af[m] = *(const bf16x8*)&lA[(wr + m * 32 + l32) * 32 + pos * 8];
#pragma unroll
    for (int n = 0; n < 2; ++n)
      bfr[n] = *(const bf16x8*)&lB[(wc + n * 32 + l32) * 32 + pos * 8];
#pragma unroll
    for (int m = 0; m < 2; ++m)
#pragma unroll
      for (int n = 0; n < 2; ++n)
        acc[m][n] = __builtin_amdgcn_mfma_f32_32x32x16_bf16(af[m], bfr[n], acc[m][n], 0, 0, 0);
  }
}

// 16x16x32 fragment quad read: 4 consecutive 16-row groups at fixed k-group, swizzled chunk.
__device__ __forceinline__ void rd4(const unsigned short* p, int rbase, int rl15, int csw,
                                    bf16x8 fr[4]) {
#pragma unroll
  for (int m = 0; m < 4; ++m)
    fr[m] = *(const bf16x8*)&p[(rbase + m * 16 + rl15) * 32 + csw * 8];
}

// 16-MFMA quadrant: af(4) x bf(4) into acc rows [0..3] of ap.
__device__ __forceinline__ void mm16(const bf16x8 af[4], const bf16x8 bf[4], f32x4 ap[][4]) {
  __builtin_amdgcn_s_setprio(1);
#pragma unroll
  for (int m = 0; m < 4; ++m)
#pragma unroll
    for (int n = 0; n < 4; ++n)
      ap[m][n] = __builtin_amdgcn_mfma_f32_16x16x32_bf16(af[m], bf[n], ap[m][n], 0, 0, 0);
  __builtin_amdgcn_s_setprio(0);
}

#define QKV_BAR  __builtin_amdgcn_s_barrier()
#define QKV_LGKM asm volatile("s_waitcnt lgkmcnt(0)" ::: "memory")
#define QKV_VM6  asm volatile("s_waitcnt vmcnt(6)" ::: "memory")
#define QKV_VM0  asm volatile("s_waitcnt vmcnt(0)" ::: "memory")

// ---------------- fp32 -> bf16 convert (x) ----------------
__global__ __launch_bounds__(256) void k_convert(const float* __restrict__ in,
                                                 unsigned short* __restrict__ out, int n4) {
  int idx = blockIdx.x * 256 + threadIdx.x;
  if (idx >= n4) return;
  float4 v = ((const float4*)in)[idx];
  short4v o;
  o.x = (short)f2bf(v.x); o.y = (short)f2bf(v.y);
  o.z = (short)f2bf(v.z); o.w = (short)f2bf(v.w);
  *(short4v*)(out + (size_t)idx * 4) = o;
}

// ---------------- W fp32 [k][n] -> bf16 Wt [n][k], 3 weights in one dispatch ----------------
__global__ __launch_bounds__(256) void k_cvt_w_t(const float* __restrict__ W0,
                                                 const float* __restrict__ W1,
                                                 const float* __restrict__ W2,
                                                 unsigned short* __restrict__ Wt3) {
  const int n0 = blockIdx.x * 64, k0 = blockIdx.y * 64, w = blockIdx.z;
  const float* W = (w == 0) ? W0 : (w == 1) ? W1 : W2;
  unsigned short* Wt = Wt3 + (size_t)w * Hn * Dn;
  __shared__ unsigned short lT[64 * 65];
  const int tid = threadIdx.x;
#pragma unroll
  for (int p = 0; p < 2; ++p) {
    int o = tid + p * 256;
    int r = o >> 3, c = (o & 7) * 8;  // r = k offset, c = n offset
    const float* src = W + (size_t)(k0 + r) * Hn + n0 + c;
    float4 v0 = *(const float4*)src;
    float4 v1 = *(const float4*)(src + 4);
    unsigned short* d = &lT[r * 65 + c];
    d[0] = f2bf(v0.x); d[1] = f2bf(v0.y); d[2] = f2bf(v0.z); d[3] = f2bf(v0.w);
    d[4] = f2bf(v1.x); d[5] = f2bf(v1.y); d[6] = f2bf(v1.z); d[7] = f2bf(v1.w);
  }
  __syncthreads();
#pragma unroll
  for (int p = 0; p < 2; ++p) {
    int o = tid + p * 256;
    int r2 = o >> 3, c2 = (o & 7) * 8;  // r2 = n offset, c2 = k offset
    bf16x8 v;
#pragma unroll
    for (int s = 0; s < 8; ++s) v[s] = (short)lT[(c2 + s) * 65 + r2];
    *(bf16x8*)(Wt + (size_t)(n0 + r2) * Dn + k0 + c2) = v;
  }
}

// ---------------- Merged QKV projection GEMM: 256x256 tile, 8-phase counted-vmcnt pipeline ----
// Per 2-K-tile iteration, 8 phases of {4-8 ds_read_b128, stage 1 piece (2 global_load_lds
// /lane), s_barrier, lgkmcnt(0), setprio(1) 16 MFMA setprio(0), s_barrier}.
// Pieces per K-tile: AL,AH,BL,BH (256x32 each). Consumption: P1{AL(m0-3),BL} P2{AL(m4-7)}
// P3{AH(m0-3),BH} P4{AH(m4-7)} (bf regs reused across each phase pair), then same on buf1.
// Stage rotation (piece staged 2 phases after its slot's last read; per-phase barriers make
// slot death block-wide): P1:t1.AH P2:t2.BL P3:t2.AL P4:t2.BH P5:t2.AH P6:t3.BL P7:t3.AL
// P8:t3.BH  (t1=2i+1, t2=2i+2, t3=2i+3).
// vmcnt(6) at P4/P8 only (2 loads/piece; 7 pieces outstanding at gate -> gate leaves 3,
// so the 4 pieces consumed in the next 4 phases have landed); never vmcnt(0) in main loop.
// Main loop #pragma unroll 1 (compact body, ~128 MFMA); final iteration peeled (R2's full
// unroll produced a ~6k-inst body -> compile blowup).
// grid = 768: XCD c = f&7; 12 n-tiles (3 weights x 4); V transposed store.
__global__ __launch_bounds__(512, 2) void gemm_qkv(const unsigned short* __restrict__ A,
                                                   const unsigned short* __restrict__ Wt3,
                                                   unsigned short* __restrict__ Q,
                                                   unsigned short* __restrict__ Kb,
                                                   unsigned short* __restrict__ Vt) {
  const int f = blockIdx.x;
  const int c = f & 7;
  const int q = f >> 3;
  const int nn = q % 12;
  const int w = nn >> 2;                     // 0=Q 1=K 2=V
  const int n0 = (nn & 3) * 256;
  const int m0 = ((q / 12) * 8 + c) * 256;   // m-tile pinned to XCD c
  const unsigned short* Bw = Wt3 + (size_t)w * Hn * Dn;
  __shared__ unsigned short lds[2][4][256 * 32];  // [buf][AL,AH,BL,BH]; buf0 = even tiles
  const int tid = threadIdx.x;
  const int lane = tid & 63, wave = tid >> 6;
  const int wr = (wave >> 2) * 128;          // wave 128-row strip
  const int wc = (wave & 3) * 64;            // wave 64-col strip
  const int rl15 = lane & 15, l4 = lane >> 4;
  const int csw = (l4 ^ (lane & 3) ^ ((lane >> 2) & 3)) & 3;  // = l4 ^ s(row)

  f32x4 acc[8][4];
#pragma unroll
  for (int m = 0; m < 8; ++m)
#pragma unroll
    for (int n = 0; n < 4; ++n) acc[m][n] = (f32x4)(0.f);

  const unsigned short* Ab = A + (size_t)m0 * Dn;
  const unsigned short* Bb = Bw + (size_t)n0 * Dn;

  unsigned short* L0AL = &lds[0][0][0];
  unsigned short* L0AH = &lds[0][1][0];
  unsigned short* L0BL = &lds[0][2][0];
  unsigned short* L0BH = &lds[0][3][0];
  unsigned short* L1AL = &lds[1][0][0];
  unsigned short* L1AH = &lds[1][1][0];
  unsigned short* L1BL = &lds[1][2][0];
  unsigned short* L1BH = &lds[1][3][0];

  // prologue: tile0 all 4 pieces + tile1 {BL,AL,BH}; VM6 leaves the 3 newest in flight
  stage256x32s(Ab +  0, Dn, L0AL, wave, lane);
  stage256x32s(Bb +  0, Dn, L0BL, wave, lane);
  stage256x32s(Ab + 32, Dn, L0AH, wave, lane);
  stage256x32s(Bb + 32, Dn, L0BH, wave, lane);
  stage256x32s(Bb + 64, Dn, L1BL, wave, lane);
  stage256x32s(Ab + 64, Dn, L1AL, wave, lane);
  stage256x32s(Bb + 96, Dn, L1BH, wave, lane);
  QKV_VM6;   // tile0's 4 pieces landed
  QKV_BAR;

  bf16x8 af[4], bf[4];
#pragma unroll 1
  for (int i = 0; i < 7; ++i) {
    const int t1 = 2 * i + 1, t2 = 2 * i + 2, t3 = 2 * i + 3;
    // P1: tile 2i (m0-3, lo); stage t1.AH
    rd4(L0AL, wr, rl15, csw, af);
    rd4(L0BL, wc, rl15, csw, bf);
    stage256x32s(Ab + t1 * 64 + 32, Dn, L1AH, wave, lane);
    QKV_BAR; QKV_LGKM; mm16(af, bf, &acc[0]); QKV_BAR;
    // P2: (m4-7, lo), bf reused; stage t2.BL
    rd4(L0AL, wr + 64, rl15, csw, af);
    stage256x32s(Bb + t2 * 64, Dn, L0BL, wave, lane);
    QKV_BAR; QKV_LGKM; mm16(af, bf, &acc[4]); QKV_BAR;
    // P3: (m0-3, hi); stage t2.AL
    rd4(L0AH, wr, rl15, csw, af);
    rd4(L0BH, wc, rl15, csw, bf);
    stage256x32s(Ab + t2 * 64, Dn, L0AL, wave, lane);
    QKV_BAR; QKV_LGKM; mm16(af, bf, &acc[0]); QKV_BAR;
    // P4: (m4-7, hi); stage t2.BH; vmcnt gate for P5-P8's pieces
    rd4(L0AH, wr + 64, rl15, csw, af);
    stage256x32s(Bb + t2 * 64 + 32, Dn, L0BH, wave, lane);
    QKV_VM6;
    QKV_BAR; QKV_LGKM; mm16(af, bf, &acc[4]); QKV_BAR;
    // P5: tile 2i+1 (m0-3, lo); stage t2.AH
    rd4(L1AL, wr, rl15, csw, af);
    rd4(L1BL, wc, rl15, csw, bf);
    stage256x32s(Ab + t2 * 64 + 32, Dn, L0AH, wave, lane);
    QKV_BAR; QKV_LGKM; mm16(af, bf, &acc[0]); QKV_BAR;
    // P6: (m4-7, lo); stage t3.BL
    rd4(L1AL, wr + 64, rl15, csw, af);
    stage256x32s(Bb + t3 * 64, Dn, L1BL, wave, lane);
    QKV_BAR; QKV_LGKM; mm16(af, bf, &acc[4]); QKV_BAR;
    // P7: (m0-3, hi); stage t3.AL
    rd4(L1AH, wr, rl15, csw, af);
    rd4(L1BH, wc, rl15, csw, bf);
    stage256x32s(Ab + t3 * 64, Dn, L1AL, wave, lane);
    QKV_BAR; QKV_LGKM; mm16(af, bf, &acc[0]); QKV_BAR;
    // P8: (m4-7, hi); stage t3.BH; vmcnt gate for next iter P1-P4
    rd4(L1AH, wr + 64, rl15, csw, af);
    stage256x32s(Bb + t3 * 64 + 32, Dn, L1BH, wave, lane);
    QKV_VM6;
    QKV_BAR; QKV_LGKM; mm16(af, bf, &acc[4]); QKV_BAR;
  }
  // peeled i=7: tiles 14 (buf0) / 15 (buf1); stage only t15.AH, drain at P4
  rd4(L0AL, wr, rl15, csw, af);
  rd4(L0BL, wc, rl15, csw, bf);
  stage256x32s(Ab + 15 * 64 + 32, Dn, L1AH, wave, lane);
  QKV_BAR; QKV_LGKM; mm16(af, bf, &acc[0]); QKV_BAR;
  rd4(L0AL, wr + 64, rl15, csw, af);
  QKV_BAR; QKV_LGKM; mm16(af, bf, &acc[4]); QKV_BAR;
  rd4(L0AH, wr, rl15, csw, af);
  rd4(L0BH, wc, rl15, csw, bf);
  QKV_BAR; QKV_LGKM; mm16(af, bf, &acc[0]); QKV_BAR;
  rd4(L0AH, wr + 64, rl15, csw, af);
  QKV_VM0;
  QKV_BAR; QKV_LGKM; mm16(af, bf, &acc[4]); QKV_BAR;
  rd4(L1AL, wr, rl15, csw, af);
  rd4(L1BL, wc, rl15, csw, bf);
  QKV_BAR; QKV_LGKM; mm16(af, bf, &acc[0]); QKV_BAR;
  rd4(L1AL, wr + 64, rl15, csw, af);
  QKV_BAR; QKV_LGKM; mm16(af, bf, &acc[4]); QKV_BAR;
  rd4(L1AH, wr, rl15, csw, af);
  rd4(L1BH, wc, rl15, csw, bf);
  QKV_BAR; QKV_LGKM; mm16(af, bf, &acc[0]); QKV_BAR;
  rd4(L1AH, wr + 64, rl15, csw, af);
  QKV_LGKM; mm16(af, bf, &acc[4]);

  // epilogue: C/D layout col=lane&15, row=l4*4+reg
  if (w != 2) {
    unsigned short* Cp = (w == 0) ? Q : Kb;
#pragma unroll
    for (int m = 0; m < 8; ++m) {
      const int row = m0 + wr + m * 16 + l4 * 4;
#pragma unroll
      for (int n = 0; n < 4; ++n) {
        const int col = n0 + wc + n * 16 + rl15;
#pragma unroll
        for (int r = 0; r < 4; ++r)
          Cp[(size_t)(row + r) * Hn + col] = f2bf(acc[m][n][r]);
      }
    }
  } else {
    // V: write transposed per-batch [h][t]; regs 0..3 = 4 consecutive t -> 8B store
    const int bb = m0 >> 11;  // tile never crosses batch (2048 % 256 == 0)
    const int tb = m0 & 2047;
#pragma unroll
    for (int m = 0; m < 8; ++m) {
      const int t0 = tb + wr + m * 16 + l4 * 4;
#pragma unroll
      for (int n = 0; n < 4; ++n) {
        const int h = n0 + wc + n * 16 + rl15;
        short4v o;
        o.x = (short)f2bf(acc[m][n][0]);
        o.y = (short)f2bf(acc[m][n][1]);
        o.z = (short)f2bf(acc[m][n][2]);
        o.w = (short)f2bf(acc[m][n][3]);
        *(short4v*)(Vt + ((size_t)bb * Hn + h) * Tn + t0) = o;
      }
    }
  }
}

// Scores: E[i][j] = exp((Q[i]·K[j])/32), causal-masked to 0, bf16. BK=64, causal tile skip.
__global__ __launch_bounds__(256) void gemm_scores(const unsigned short* __restrict__ Q,
                                                   const unsigned short* __restrict__ K,
                                                   unsigned short* __restrict__ S) {
  const int f = blockIdx.x;
  const int b = f & 7;
  const int q = f >> 3;
  const int rt = 15 - (q & 15);
  const int ct = q >> 4;
  if (ct > rt) return;
  const int j0 = ct * 128, i0 = rt * 128;
  const unsigned short* Qb = Q + (size_t)b * Tn * Hn;
  const unsigned short* Kp = K + (size_t)b * Tn * Hn;
  unsigned short* Sb = S + (size_t)b * Tn * Tn;
  __shared__ unsigned short lA[2][128 * 32];
  __shared__ unsigned short lB[2][128 * 32];
  const int tid = threadIdx.x;
  const int lane = tid & 63, wave = tid >> 6;
  const int wr = (wave >> 1) * 64, wc = (wave & 1) * 64;
  const int l32 = lane & 31, half = lane >> 5;

  f32x16 acc[2][2];
#pragma unroll
  for (int m = 0; m < 2; ++m)
#pragma unroll
    for (int n = 0; n < 2; ++n) acc[m][n] = (f32x16)(0.f);

  for (int kt = 0; kt < Hn / 64; ++kt) {
    stage128x64s(Qb + (size_t)i0 * Hn + kt * 64, Hn, lA[0], lA[1], wave, lane);
    stage128x64s(Kp + (size_t)j0 * Hn + kt * 64, Hn, lB[0], lB[1], wave, lane);
    __syncthreads();
    mma_bk32(lA[0], lB[0], wr, wc, l32, half, acc);
    mma_bk32(lA[1], lB[1], wr, wc, l32, half, acc);
    __syncthreads();
  }
  // E = exp(s/32), masked above diagonal. No row-max needed: s ~ N(0,1), f32-safe.
#pragma unroll
  for (int m = 0; m < 2; ++m)
#pragma unroll
    for (int n = 0; n < 2; ++n) {
      int col = j0 + wc + n * 32 + l32;
#pragma unroll
      for (int qd = 0; qd < 4; ++qd) {
        int rb = i0 + wr + m * 32 + 8 * qd + 4 * half;
#pragma unroll
        for (int rr = 0; rr < 4; ++rr) {
          int row = rb + rr;
          float e = (col <= row) ? __expf(acc[m][n][qd * 4 + rr] * 0.03125f) : 0.f;
          Sb[(size_t)row * Tn + col] = f2bf(e);
        }
      }
    }
}

// ---------------- row sums of E (softmax denominators) ----------------
__global__ __launch_bounds__(256) void k_rowsum(const unsigned short* __restrict__ S,
                                                float* __restrict__ l) {
  const int b = blockIdx.y;
  const int i = blockIdx.x * 4 + (threadIdx.x >> 6);
  const int lane = threadIdx.x & 63;
  const unsigned short* row = S + ((size_t)b * Tn + i) * (size_t)Tn;
  const int npad = ((i >> 7) + 1) << 7;
  float s = 0.f;
  for (int j0 = 0; j0 < npad; j0 += 512) {
    int j = j0 + lane * 8;
    if (j < npad) {
      bf16x8 v = *(const bf16x8*)(row + j);
#pragma unroll
      for (int t = 0; t < 8; ++t) s += bf2f((unsigned short)v[t]);
    }
  }
#pragma unroll
  for (int off = 32; off > 0; off >>= 1) s += __shfl_down(s, off);
  if (lane == 0) l[(size_t)b * Tn + i] = s;
}

// Output: O[i][h] = (1/l_i) * sum_k E[i][k] * Vt[h][k], causal k limit, BK=64, 32x32 MFMA.
__global__ __launch_bounds__(256) void gemm_out(const unsigned short* __restrict__ P,
                                                const unsigned short* __restrict__ Vt,
                                                const float* __restrict__ lbuf,
                                                float* __restrict__ O) {
  const int f = blockIdx.x;
  const int b = f & 7;
  const int q = f >> 3;
  const int n0 = (q & 7) * 128;
  const int rt = 15 - (q >> 3);
  const int i0 = rt * 128;
  const int nkt = (rt + 1) * 2;  // BK=64 iters: k < (rt+1)*128
  const unsigned short* Pb = P + (size_t)b * Tn * Tn;
  const unsigned short* Vb = Vt + (size_t)b * Tn * Hn;
  __shared__ unsigned short lA[2][128 * 32];
  __shared__ unsigned short lB[2][128 * 32];
  const int tid = threadIdx.x;
  const int lane = tid & 63, wave = tid >> 6;
  const int wr = (wave >> 1) * 64, wc = (wave & 1) * 64;
  const int l32 = lane & 31, half = lane >> 5;

  f32x16 acc[2][2];
#pragma unroll
  for (int m = 0; m < 2; ++m)
#pragma unroll
    for (int n = 0; n < 2; ++n) acc[m][n] = (f32x16)(0.f);

  for (int kt = 0; kt < nkt; ++kt) {
    stage128x64s(Pb + (size_t)i0 * Tn + kt * 64, Tn, lA[0], lA[1], wave, lane);
    stage128x64s(Vb + (size_t)n0 * Tn + kt * 64, Tn, lB[0], lB[1], wave, lane);
    __syncthreads();
    mma_bk32(lA[0], lB[0], wr, wc, l32, half, acc);
    mma_bk32(lA[1], lB[1], wr, wc, l32, half, acc);
    __syncthreads();
  }
#pragma unroll
  for (int m = 0; m < 2; ++m)
#pragma unroll
    for (int n = 0; n < 2; ++n) {
      int col = n0 + wc + n * 32 + l32;
#pragma unroll
      for (int qd = 0; qd < 4; ++qd) {
        int rb = i0 + wr + m * 32 + 8 * qd + 4 * half;
        float4 lv = *(const float4*)&lbuf[(size_t)b * Tn + rb];  // rb % 4 == 0
#pragma unroll
        for (int rr = 0; rr < 4; ++rr) {
          float inv = 1.f / ((&lv.x)[rr]);
          O[((size_t)b * Tn + rb + rr) * Hn + col] = acc[m][n][qd * 4 + rr] * inv;
        }
      }
    }
}

extern "C" void kernel_launch(void* const* d_in, const int* in_sizes, int n_in,
                              void* d_out, int out_size, void* d_ws, size_t ws_size,
                              hipStream_t stream) {
  const float* x  = (const float*)d_in[0];
  const float* Wq = (const float*)d_in[1];
  const float* Wk = (const float*)d_in[2];
  const float* Wv = (const float*)d_in[3];
  float* out = (float*)d_out;

  // workspace layout (bytes); total 198 MiB
  char* ws = (char*)d_ws;
  const size_t MiB = 1024 * 1024;
  unsigned short* Wt3 = (unsigned short*)(ws + 0 * MiB);    // 3 x 2 MiB, stacked q,k,v
  unsigned short* xb  = (unsigned short*)(ws + 6 * MiB);    // 32 MiB; dead after projections
  unsigned short* Qb  = (unsigned short*)(ws + 38 * MiB);
  unsigned short* Kb  = (unsigned short*)(ws + 70 * MiB);
  unsigned short* Vt  = (unsigned short*)(ws + 102 * MiB);  // V, transposed per-batch [h][t]
  unsigned short* S   = (unsigned short*)(ws + 134 * MiB);  // 64 MiB, holds E = exp(scores)
  float*          lrow = (float*)(ws + 6 * MiB);            // 64 KiB in xb's dead region

  // 1. convert x to bf16
  {
    int n4 = (Mn * Dn) / 4;
    k_convert<<<dim3(n4 / 256), 256, 0, stream>>>(x, xb, n4);
  }
  // 2. convert+transpose all 3 weights (one dispatch)
  {
    dim3 g(Hn / 64, Dn / 64, 3);
    k_cvt_w_t<<<g, 256, 0, stream>>>(Wq, Wk, Wv, Wt3);
  }
  // 3. merged Q/K/V projections (V stored transposed), 8-phase pipelined 256^2 tiles
  {
    gemm_qkv<<<dim3(768), 512, 0, stream>>>(xb, Wt3, Qb, Kb, Vt);
  }
  // 4. scores -> E = exp(s), causal-masked
  {
    gemm_scores<<<dim3(2048), 256, 0, stream>>>(Qb, Kb, S);
  }
  // 5. row sums (softmax denominators)
  {
    k_rowsum<<<dim3(Tn / 4, Bn), 256, 0, stream>>>(S, lrow);
  }
  // 6. output with 1/l scaling
  {
    gemm_out<<<dim3(1024), 256, 0, stream>>>(S, Vt, lrow, out);
  }
}